// Round 1
// baseline (314.029 us; speedup 1.0000x reference)
//
#include <hip/hip_runtime.h>
#include <hip/hip_bf16.h>

#define N_NODES 30000
#define N_EDGES 480000
#define IN_CH   1024
#define OUT_CH  128
#define MAX_DEG 48

typedef float   f32x4  __attribute__((ext_vector_type(4)));
typedef __bf16  bf16x8 __attribute__((ext_vector_type(8)));
typedef unsigned short ushort8 __attribute__((ext_vector_type(8)));

__device__ __forceinline__ unsigned short f2bf(float f) {
  unsigned int u = __builtin_bit_cast(unsigned int, f);
  u += 0x7fffu + ((u >> 16) & 1u);          // RTNE
  return (unsigned short)(u >> 16);
}

// ---------------------------------------------------------------------------
// Kernel 1: W [1024][128] fp32  ->  Wt [128][1024] bf16 (transposed)
// ---------------------------------------------------------------------------
__global__ __launch_bounds__(256) void convert_W(const float* __restrict__ W,
                                                 unsigned short* __restrict__ Wt) {
  int idx = blockIdx.x * 256 + threadIdx.x;      // over Wt, 131072 elems
  int n = idx >> 10;                              // 0..127
  int k = idx & 1023;                             // 0..1023
  Wt[idx] = f2bf(W[k * OUT_CH + n]);
}

// ---------------------------------------------------------------------------
// Kernel 2: adjacency build (edges + self-loops), atomic slot assignment
// ---------------------------------------------------------------------------
__global__ __launch_bounds__(256) void build_adj(const int* __restrict__ ei,
                                                 int* __restrict__ deg,
                                                 int* __restrict__ adj) {
  int i = blockIdx.x * blockDim.x + threadIdx.x;
  const int total = N_EDGES + N_NODES;
  if (i >= total) return;
  int src, dst;
  if (i < N_EDGES) { src = ei[i]; dst = ei[N_EDGES + i]; }
  else             { src = i - N_EDGES; dst = src; }     // self-loop
  int slot = atomicAdd(&deg[dst], 1);
  if (slot < MAX_DEG) adj[dst * MAX_DEG + slot] = src;
}

// ---------------------------------------------------------------------------
// Kernel 3: h = x @ W  via bf16 MFMA, LDS-free.
// Block = 256 thr (4 waves), tile 64 rows x 128 cols, K-loop over 1024.
// Wave w owns rows m0+16w..+15. A frags direct from x (fp32->bf16 in regs),
// B frags direct from L2-resident Wt.
// ---------------------------------------------------------------------------
__global__ __launch_bounds__(256) void gemm_h(const float* __restrict__ x,
                                              const unsigned short* __restrict__ Wt,
                                              float* __restrict__ h) {
  const int tid  = threadIdx.x;
  const int wave = tid >> 6;
  const int lane = tid & 63;
  const int l16  = lane & 15;
  const int g4   = lane >> 4;
  const int m0   = blockIdx.x * 64;
  const int arow = m0 + wave * 16 + l16;
  const float* aptr = x + (size_t)(arow < N_NODES ? arow : 0) * IN_CH + g4 * 8;
  const unsigned short* bptr = Wt + l16 * IN_CH + g4 * 8;

  f32x4 acc[8];
#pragma unroll
  for (int i = 0; i < 8; ++i) acc[i] = (f32x4){0.f, 0.f, 0.f, 0.f};

  for (int k0 = 0; k0 < IN_CH; k0 += 32) {
    f32x4 a0 = *(const f32x4*)(aptr + k0);
    f32x4 a1 = *(const f32x4*)(aptr + k0 + 4);
    ushort8 af;
    af[0] = f2bf(a0[0]); af[1] = f2bf(a0[1]); af[2] = f2bf(a0[2]); af[3] = f2bf(a0[3]);
    af[4] = f2bf(a1[0]); af[5] = f2bf(a1[1]); af[6] = f2bf(a1[2]); af[7] = f2bf(a1[3]);
    bf16x8 av = __builtin_bit_cast(bf16x8, af);
#pragma unroll
    for (int nn = 0; nn < 8; ++nn) {
      ushort8 bu = *(const ushort8*)(bptr + nn * 16 * IN_CH + k0);
      bf16x8 bv = __builtin_bit_cast(bf16x8, bu);
      acc[nn] = __builtin_amdgcn_mfma_f32_16x16x32_bf16(av, bv, acc[nn], 0, 0, 0);
    }
  }

  // C/D layout (verified m89/m91): col = lane&15, row = (lane>>4)*4 + i
  const int crow = m0 + wave * 16 + g4 * 4;
#pragma unroll
  for (int nn = 0; nn < 8; ++nn) {
#pragma unroll
    for (int i = 0; i < 4; ++i) {
      int r = crow + i;
      if (r < N_NODES) h[(size_t)r * OUT_CH + nn * 16 + l16] = acc[nn][i];
    }
  }
}

// ---------------------------------------------------------------------------
// Kernel 4: per-node, per-channel lower median via register sorting network
// ---------------------------------------------------------------------------
template <int NS>
__device__ __forceinline__ void batcher_sort(float (&a)[NS]) {
  // Batcher odd-even mergesort, all indices compile-time after unrolling.
#pragma unroll
  for (int p = 1; p < NS; p <<= 1) {
#pragma unroll
    for (int k = p; k >= 1; k >>= 1) {
#pragma unroll
      for (int j = k % p; j + k < NS; j += 2 * k) {
#pragma unroll
        for (int i = 0; i < k; ++i) {
          if (i + j + k < NS) {
            if ((i + j) / (2 * p) == (i + j + k) / (2 * p)) {
              float lo = fminf(a[i + j], a[i + j + k]);
              float hi = fmaxf(a[i + j], a[i + j + k]);
              a[i + j] = lo;
              a[i + j + k] = hi;
            }
          }
        }
      }
    }
  }
}

template <int NS>
__device__ __forceinline__ float med_n(const float* __restrict__ h,
                                       const int* nbrs, int d, int m, int ch) {
  float a[NS];
#pragma unroll
  for (int j = 0; j < NS; ++j) {
    if (j < d) a[j] = h[(size_t)nbrs[j] * OUT_CH + ch];
    else       a[j] = 1e30f;
  }
  batcher_sort<NS>(a);
  float med = a[0];
#pragma unroll
  for (int j = 1; j < NS; ++j) med = (j == m) ? a[j] : med;
  return med;
}

__global__ __launch_bounds__(128) void median_kernel(const float* __restrict__ h,
                                                     const int* __restrict__ adj,
                                                     const int* __restrict__ deg,
                                                     const float* __restrict__ b,
                                                     float* __restrict__ out) {
  __shared__ int nbrs[64];
  const int node = blockIdx.x;
  const int ch   = threadIdx.x;
  int d = deg[node];
  if (d > MAX_DEG) d = MAX_DEG;
  if (ch < 64) nbrs[ch] = (ch < d && ch < MAX_DEG) ? adj[node * MAX_DEG + ch] : 0;
  __syncthreads();
  const int m = (d - 1) >> 1;   // lower median index; d >= 1 (self-loop)

  float med;
  if (d <= 8)       med = med_n<8>(h, nbrs, d, m, ch);
  else if (d <= 16) med = med_n<16>(h, nbrs, d, m, ch);
  else if (d <= 32) med = med_n<32>(h, nbrs, d, m, ch);
  else              med = med_n<64>(h, nbrs, d, m, ch);

  out[(size_t)node * OUT_CH + ch] = med + b[ch];
}

// ---------------------------------------------------------------------------
extern "C" void kernel_launch(void* const* d_in, const int* in_sizes, int n_in,
                              void* d_out, int out_size, void* d_ws, size_t ws_size,
                              hipStream_t stream) {
  const float* x  = (const float*)d_in[0];
  const int*   ei = (const int*)d_in[1];   // int32 (JAX x64 disabled)
  const float* W  = (const float*)d_in[2];
  const float* b  = (const float*)d_in[3];
  float* out = (float*)d_out;

  char* ws = (char*)d_ws;
  float*          h   = (float*)ws;                                  // 15,360,000 B
  unsigned short* Wt  = (unsigned short*)(ws + 15360000);             //    262,144 B
  int*            deg = (int*)(ws + 15360000 + 262144);               //    120,000 B
  int*            adj = (int*)(ws + 15360000 + 262144 + 120000);      //  5,760,000 B

  hipMemsetAsync(deg, 0, N_NODES * sizeof(int), stream);
  convert_W<<<dim3(131072 / 256), dim3(256), 0, stream>>>(W, Wt);
  build_adj<<<dim3((N_EDGES + N_NODES + 255) / 256), dim3(256), 0, stream>>>(ei, deg, adj);
  gemm_h<<<dim3((N_NODES + 63) / 64), dim3(256), 0, stream>>>(x, Wt, h);
  median_kernel<<<dim3(N_NODES), dim3(128), 0, stream>>>(h, adj, deg, b, out);
}